// Round 6
// baseline (158.457 us; speedup 1.0000x reference)
//
#include <hip/hip_runtime.h>

#define B   2
#define N   32768
#define NC  1024
#define S   32
#define NSP (NC * S)   // 32768

#define CHUNK 2048              // xyz rows staged per block (64 KB)
#define NCH   (N / CHUNK)       // 16
#define BLKT  512               // 8 waves
#define FR    4                 // B-fragments (col tiles) per wave
#define COLS_BLK (8 * FR * 32)  // 1024
#define GRIDX (NSP / COLS_BLK)  // 32

#define PJ  8                   // points per thread in k_p2c
#define CSL 256                 // centers per slice in k_p2c

typedef __attribute__((ext_vector_type(8)))  short short8v;
typedef __attribute__((ext_vector_type(16))) float f32x16;
typedef const __attribute__((address_space(1))) void gvoid_t;
typedef __attribute__((address_space(3))) void svoid_t;

static __device__ __forceinline__ unsigned short f2b(float x) {
    unsigned u = __float_as_uint(x);
    return (unsigned short)((u + 0x7FFFu + ((u >> 16) & 1u)) >> 16);   // RNE
}
static __device__ __forceinline__ float b2f(unsigned short u) {
    return __uint_as_float(((unsigned)u) << 16);
}
static __device__ __forceinline__ float min3f(float a, float b, float c) {
    return fminf(fminf(a, b), c);   // clang fuses to v_min3_f32
}

// ws layout: Afrag 2MB | best u64 512KB | minsq u32 256KB | acc+counter 32B

// ---- kernel 1: build A-fragments + init best/minsq/acc -------------------
__global__ __launch_bounds__(256) void k_prep(const float* __restrict__ xyz,
                                              unsigned short* __restrict__ Afrag,
                                              unsigned long long* __restrict__ best,
                                              unsigned* __restrict__ minsq,
                                              unsigned* __restrict__ accw) {
    int i = blockIdx.x * 256 + threadIdx.x;   // [0, B*N) == [0, B*NSP)
    if (i < 2) accw[i] = 0u;                  // acc float + counter
    best[i]  = ~0ull;
    minsq[i] = 0x7F800000u;                   // +inf bits

    const float* q = xyz + (size_t)i * 3;
    float qx = q[0], qy = q[1], qz = q[2];
    float h = 0.5f * (qx * qx + qy * qy + qz * qz);
    unsigned short xh = f2b(-qx), yh = f2b(-qy), zh = f2b(-qz);
    unsigned short xl = f2b(-qx - b2f(xh));
    unsigned short yl = f2b(-qy - b2f(yh));
    unsigned short zl = f2b(-qz - b2f(zh));
    unsigned short hh = f2b(h), hl = f2b(h - b2f(hh));

    int b = i >> 15, j = i & (N - 1);
    int tile = j >> 5, r = j & 31;
    unsigned short* base = Afrag + ((size_t)b * N + (size_t)tile * 32) * 16;
    uint4 s0, s1;
    s0.x = (unsigned)xh | ((unsigned)yh << 16);
    s0.y = (unsigned)zh | ((unsigned)xl << 16);
    s0.z = (unsigned)yl | ((unsigned)zl << 16);
    s0.w = (unsigned)xh | ((unsigned)yh << 16);
    s1.x = (unsigned)zh | ((unsigned)hh << 16);
    s1.y = (unsigned)hl;
    s1.z = 0u; s1.w = 0u;
    *(uint4*)(base + (size_t)r * 8)        = s0;   // k=0..7   lane r
    *(uint4*)(base + (size_t)(r + 32) * 8) = s1;   // k=8..15  lane r+32
}

// ---- kernel 2: argmin over a 256-center slice, 8 points/thread -----------
__global__ __launch_bounds__(256) void k_p2c(const float* __restrict__ centers,
                                             const float* __restrict__ xyz,
                                             unsigned long long* __restrict__ best) {
    __shared__ float4 c4[CSL];
    const int b = blockIdx.z, qb = blockIdx.y, tid = threadIdx.x;

    const float* cb = centers + ((size_t)b * NC + qb * CSL) * 3;
    for (int g = tid; g < CSL / 4; g += 256) {
        float4 f0 = ((const float4*)cb)[g * 3 + 0];
        float4 f1 = ((const float4*)cb)[g * 3 + 1];
        float4 f2 = ((const float4*)cb)[g * 3 + 2];
        float x0 = f0.x, y0 = f0.y, z0 = f0.z;
        float x1 = f0.w, y1 = f1.x, z1 = f1.y;
        float x2 = f1.z, y2 = f1.w, z2 = f2.x;
        float x3 = f2.y, y3 = f2.z, z3 = f2.w;
        c4[g * 4 + 0] = make_float4(x0, y0, z0, 0.5f * (x0 * x0 + y0 * y0 + z0 * z0));
        c4[g * 4 + 1] = make_float4(x1, y1, z1, 0.5f * (x1 * x1 + y1 * y1 + z1 * z1));
        c4[g * 4 + 2] = make_float4(x2, y2, z2, 0.5f * (x2 * x2 + y2 * y2 + z2 * z2));
        c4[g * 4 + 3] = make_float4(x3, y3, z3, 0.5f * (x3 * x3 + y3 * y3 + z3 * z3));
    }
    __syncthreads();

    // 8 points per thread, stride-256 within a 2048-point panel
    const int pbase = blockIdx.x * (256 * PJ) + tid;
    float px[PJ], py[PJ], pz[PJ], tmin[PJ];
    int imin[PJ];
    #pragma unroll
    for (int k = 0; k < PJ; ++k) {
        const float* p = xyz + ((size_t)b * N + pbase + k * 256) * 3;
        px[k] = p[0]; py[k] = p[1]; pz[k] = p[2];
        tmin[k] = 1e30f; imin[k] = 0;
    }

    #pragma unroll 2
    for (int c = 0; c < CSL; ++c) {
        float4 q = c4[c];
        #pragma unroll
        for (int k = 0; k < PJ; ++k) {
            float t = q.w - px[k] * q.x - py[k] * q.y - pz[k] * q.z;
            bool lt = t < tmin[k];
            tmin[k] = lt ? t : tmin[k];
            imin[k] = lt ? c : imin[k];
        }
    }

    #pragma unroll
    for (int k = 0; k < PJ; ++k) {
        unsigned bits = __float_as_uint(tmin[k]);
        unsigned ord  = (bits & 0x80000000u) ? ~bits : (bits | 0x80000000u);
        unsigned long long key =
            ((unsigned long long)ord << 32) | (unsigned)(qb * CSL + imin[k]);
        atomicMin(best + (size_t)b * N + pbase + k * 256, key);
    }
}

// ---- kernel 3: MFMA (row-chunk x col-tile grid) -> u32 atomicMin ---------
__global__ __launch_bounds__(BLKT) void k_sp2p(const float* __restrict__ sp,
                                               const unsigned short* __restrict__ Afrag,
                                               unsigned* __restrict__ minsq) {
    __shared__ unsigned short lds[CHUNK * 16];   // 64 KB
    const int b = blockIdx.z, chunk = blockIdx.y;
    const int tid = threadIdx.x, wid = tid >> 6, lane = tid & 63;

    // stage 64 KB: 8 iters x (512 lanes x 16 B)
    const char* src = (const char*)(Afrag +
                        ((size_t)b * N + (size_t)chunk * CHUNK) * 16);
    #pragma unroll
    for (int it = 0; it < 8; ++it) {
        int off = it * 8192 + wid * 1024;
        __builtin_amdgcn_global_load_lds((gvoid_t*)(src + off + lane * 16),
                                         (svoid_t*)((char*)lds + off), 16, 0, 0);
    }

    // FR B-fragments per wave (overlaps staging latency)
    const int colbase = blockIdx.x * COLS_BLK + wid * (FR * 32) + (lane & 31);
    float pp[FR]; short8v bf[FR];
    #pragma unroll
    for (int f = 0; f < FR; ++f) {
        const float* p = sp + ((size_t)b * NSP + colbase + f * 32) * 3;
        float qx = p[0], qy = p[1], qz = p[2];
        pp[f] = qx * qx + qy * qy + qz * qz;
        unsigned short xh = f2b(qx), yh = f2b(qy), zh = f2b(qz);
        unsigned short xl = f2b(qx - b2f(xh));
        unsigned short yl = f2b(qy - b2f(yh));
        unsigned short zl = f2b(qz - b2f(zh));
        short8v v;
        if (lane < 32) {
            v[0] = (short)xh; v[1] = (short)yh; v[2] = (short)zh;
            v[3] = (short)xh; v[4] = (short)yh; v[5] = (short)zh;
            v[6] = (short)xl; v[7] = (short)yl;
        } else {
            v[0] = (short)zl; v[1] = (short)0x3F80; v[2] = (short)0x3F80;
            v[3] = 0; v[4] = 0; v[5] = 0; v[6] = 0; v[7] = 0;
        }
        bf[f] = v;
    }
    f32x16 zero;
    #pragma unroll
    for (int i = 0; i < 16; ++i) zero[i] = 0.0f;

    float run[FR];
    #pragma unroll
    for (int f = 0; f < FR; ++f) run[f] = 1e30f;

    __syncthreads();   // staging complete

    const unsigned short* ap = lds + lane * 8;
    #pragma unroll 1
    for (int t = 0; t < CHUNK / 32; ++t) {
        short8v a = *(const short8v*)(ap + (size_t)t * 512);
        #pragma unroll
        for (int f = 0; f < FR; ++f) {
            f32x16 d = __builtin_amdgcn_mfma_f32_32x32x16_bf16(a, bf[f], zero, 0, 0, 0);
            float r0 = min3f(d[0],  d[1],  d[2]);
            float r1 = min3f(d[3],  d[4],  d[5]);
            float r2 = min3f(d[6],  d[7],  d[8]);
            float r3 = min3f(d[9],  d[10], d[11]);
            float r4 = min3f(d[12], d[13], d[14]);
            float r5 = min3f(r0, r1, d[15]);
            float r6 = min3f(r2, r3, r4);
            run[f] = min3f(run[f], r5, r6);
        }
    }

    // lanes l, l^32 hold the same col: combine, then one atomic per col
    #pragma unroll
    for (int f = 0; f < FR; ++f)
        run[f] = fminf(run[f], __shfl_xor(run[f], 32, 64));
    if (lane < 32) {
        unsigned* mb = minsq + (size_t)b * NSP + colbase;
        #pragma unroll
        for (int f = 0; f < FR; ++f) {
            float sq = fmaxf(2.0f * run[f] + pp[f], 0.0f);
            atomicMin(mb + f * 32, __float_as_uint(sq));
        }
    }
}

// ---- kernel 4: p2c finalize + group-max + ticketed final scalar ----------
__global__ __launch_bounds__(256) void k_fin(const unsigned long long* __restrict__ best,
                                             const unsigned* __restrict__ minsq,
                                             const float* __restrict__ xyz,
                                             const float* __restrict__ radius,
                                             float* __restrict__ acc,
                                             unsigned* __restrict__ counter,
                                             float* __restrict__ out) {
    const int tid = threadIdx.x;
    const int i = blockIdx.x * 256 + tid;   // [0, B*N) == [0, B*NSP)
    const int b = i >> 15;

    // p2c term
    unsigned long long k = best[i];
    int idx = (int)(k & 0xFFFFFFFFu);
    unsigned ord  = (unsigned)(k >> 32);
    unsigned bits = (ord & 0x80000000u) ? (ord ^ 0x80000000u) : ~ord;
    float tmin = __uint_as_float(bits);
    const float* p = xyz + (size_t)i * 3;
    float pp = p[0] * p[0] + p[1] * p[1] + p[2] * p[2];
    float cdp = sqrtf(fmaxf(2.0f * tmin + pp, 1e-12f));
    float val = fmaxf(cdp - radius[(size_t)b * NC + idx], 0.0f);

    // c2p term: group of S=32 consecutive minsq entries = one 32-lane half
    float cd = sqrtf(fmaxf(__uint_as_float(minsq[i]), 1e-12f));
    #pragma unroll
    for (int o = 16; o > 0; o >>= 1) cd = fmaxf(cd, __shfl_xor(cd, o, 64));

    float contrib = val * (1.0f / N) +
                    (((tid & 31) == 0) ? cd * (1.0f / NC) : 0.0f);
    #pragma unroll
    for (int o = 32; o > 0; o >>= 1) contrib += __shfl_down(contrib, o);
    __shared__ float wsum[4];
    if ((tid & 63) == 0) wsum[tid >> 6] = contrib;
    __syncthreads();
    if (tid == 0) atomicAdd(&acc[0], wsum[0] + wsum[1] + wsum[2] + wsum[3]);

    __shared__ int lastf;
    if (tid == 0) {
        __threadfence();
        unsigned old = atomicAdd(counter, 1u);
        lastf = (old == (unsigned)(gridDim.x - 1));
    }
    __syncthreads();
    if (lastf && tid == 0)
        out[0] = atomicAdd(&acc[0], 0.0f) * (1.0f / B);
}

extern "C" void kernel_launch(void* const* d_in, const int* in_sizes, int n_in,
                              void* d_out, int out_size, void* d_ws, size_t ws_size,
                              hipStream_t stream) {
    const float* centers = (const float*)d_in[0];
    const float* radius  = (const float*)d_in[1];
    const float* xyz     = (const float*)d_in[2];
    const float* sp      = (const float*)d_in[3];
    float* out = (float*)d_out;

    unsigned short*     Afrag = (unsigned short*)d_ws;                        // 2 MB
    unsigned long long* best  = (unsigned long long*)((char*)d_ws + (size_t)B * N * 32);
    unsigned* minsq  = (unsigned*)((char*)best + (size_t)B * N * 8);          // 256 KB
    float*    acc    = (float*)((char*)minsq + (size_t)B * NSP * 4);
    unsigned* counter = (unsigned*)acc + 1;

    hipLaunchKernelGGL(k_prep, dim3(B * N / 256), dim3(256), 0, stream,
                       xyz, Afrag, best, minsq, (unsigned*)acc);
    hipLaunchKernelGGL(k_p2c, dim3(N / (256 * PJ), NC / CSL, B), dim3(256), 0, stream,
                       centers, xyz, best);
    hipLaunchKernelGGL(k_sp2p, dim3(GRIDX, NCH, B), dim3(BLKT), 0, stream,
                       sp, Afrag, minsq);
    hipLaunchKernelGGL(k_fin, dim3(B * N / 256), dim3(256), 0, stream,
                       best, minsq, xyz, radius, acc, counter, out);
}

// Round 7
// 143.245 us; speedup vs baseline: 1.1062x; 1.1062x over previous
//
#include <hip/hip_runtime.h>

#define B   2
#define N   32768
#define NC  1024
#define S   32
#define NSP (NC * S)   // 32768

#define CHUNK 2048              // xyz rows staged per block (64 KB)
#define NCH   (N / CHUNK)       // 16
#define BLKT  512               // 8 waves
#define FR    4                 // B-fragments (col tiles) per wave
#define COLS_BLK (8 * FR * 32)  // 1024
#define GRIDX (NSP / COLS_BLK)  // 32

#define PJ  8                   // points per thread in k_p2c
#define CSL 64                  // centers per slice in k_p2c

typedef __attribute__((ext_vector_type(8)))  short short8v;
typedef __attribute__((ext_vector_type(16))) float f32x16;
typedef const __attribute__((address_space(1))) void gvoid_t;
typedef __attribute__((address_space(3))) void svoid_t;

static __device__ __forceinline__ unsigned short f2b(float x) {
    unsigned u = __float_as_uint(x);
    return (unsigned short)((u + 0x7FFFu + ((u >> 16) & 1u)) >> 16);   // RNE
}
static __device__ __forceinline__ float b2f(unsigned short u) {
    return __uint_as_float(((unsigned)u) << 16);
}
static __device__ __forceinline__ float min3f(float a, float b, float c) {
    return fminf(fminf(a, b), c);   // clang fuses to v_min3_f32
}

// MFMA with dst forced to VGPRs (avoids 16x v_accvgpr_read per MFMA).
// s_nop 7+7+1 = 18 cycles covers the 16-pass-MFMA -> VALU-read-D hazard,
// since inline asm is opaque to the hazard recognizer. Bubbles hidden by
// 8 waves/SIMD occupancy.
static __device__ __forceinline__ f32x16 mfma_v(short8v a, short8v b) {
    f32x16 d;
    asm("v_mfma_f32_32x32x16_bf16 %0, %1, %2, 0\n\t"
        "s_nop 7\n\t"
        "s_nop 7\n\t"
        "s_nop 1"
        : "=v"(d) : "v"(a), "v"(b));
    return d;
}

// ws layout: Afrag 2MB | best u64 512KB | minsq u32 256KB | acc+counter 32B

// ---- kernel 1: build A-fragments + init best/minsq/acc -------------------
__global__ __launch_bounds__(256) void k_prep(const float* __restrict__ xyz,
                                              unsigned short* __restrict__ Afrag,
                                              unsigned long long* __restrict__ best,
                                              unsigned* __restrict__ minsq,
                                              unsigned* __restrict__ accw) {
    int i = blockIdx.x * 256 + threadIdx.x;   // [0, B*N) == [0, B*NSP)
    if (i < 2) accw[i] = 0u;                  // acc float + counter
    best[i]  = ~0ull;
    minsq[i] = 0x7F800000u;                   // +inf bits

    const float* q = xyz + (size_t)i * 3;
    float qx = q[0], qy = q[1], qz = q[2];
    float h = 0.5f * (qx * qx + qy * qy + qz * qz);
    unsigned short xh = f2b(-qx), yh = f2b(-qy), zh = f2b(-qz);
    unsigned short xl = f2b(-qx - b2f(xh));
    unsigned short yl = f2b(-qy - b2f(yh));
    unsigned short zl = f2b(-qz - b2f(zh));
    unsigned short hh = f2b(h), hl = f2b(h - b2f(hh));

    int b = i >> 15, j = i & (N - 1);
    int tile = j >> 5, r = j & 31;
    unsigned short* base = Afrag + ((size_t)b * N + (size_t)tile * 32) * 16;
    uint4 s0, s1;
    s0.x = (unsigned)xh | ((unsigned)yh << 16);
    s0.y = (unsigned)zh | ((unsigned)xl << 16);
    s0.z = (unsigned)yl | ((unsigned)zl << 16);
    s0.w = (unsigned)xh | ((unsigned)yh << 16);
    s1.x = (unsigned)zh | ((unsigned)hh << 16);
    s1.y = (unsigned)hl;
    s1.z = 0u; s1.w = 0u;
    *(uint4*)(base + (size_t)r * 8)        = s0;   // k=0..7   lane r
    *(uint4*)(base + (size_t)(r + 32) * 8) = s1;   // k=8..15  lane r+32
}

// ---- kernel 2: argmin over a 64-center slice, 8 points/thread ------------
__global__ __launch_bounds__(256) void k_p2c(const float* __restrict__ centers,
                                             const float* __restrict__ xyz,
                                             unsigned long long* __restrict__ best) {
    __shared__ float4 c4[CSL];
    const int b = blockIdx.z, qb = blockIdx.y, tid = threadIdx.x;

    const float* cb = centers + ((size_t)b * NC + qb * CSL) * 3;
    for (int g = tid; g < CSL / 4; g += 256) {
        float4 f0 = ((const float4*)cb)[g * 3 + 0];
        float4 f1 = ((const float4*)cb)[g * 3 + 1];
        float4 f2 = ((const float4*)cb)[g * 3 + 2];
        float x0 = f0.x, y0 = f0.y, z0 = f0.z;
        float x1 = f0.w, y1 = f1.x, z1 = f1.y;
        float x2 = f1.z, y2 = f1.w, z2 = f2.x;
        float x3 = f2.y, y3 = f2.z, z3 = f2.w;
        c4[g * 4 + 0] = make_float4(x0, y0, z0, 0.5f * (x0 * x0 + y0 * y0 + z0 * z0));
        c4[g * 4 + 1] = make_float4(x1, y1, z1, 0.5f * (x1 * x1 + y1 * y1 + z1 * z1));
        c4[g * 4 + 2] = make_float4(x2, y2, z2, 0.5f * (x2 * x2 + y2 * y2 + z2 * z2));
        c4[g * 4 + 3] = make_float4(x3, y3, z3, 0.5f * (x3 * x3 + y3 * y3 + z3 * z3));
    }
    __syncthreads();

    // 8 points per thread, stride-256 within a 2048-point panel
    const int pbase = blockIdx.x * (256 * PJ) + tid;
    float px[PJ], py[PJ], pz[PJ], tmin[PJ];
    int imin[PJ];
    #pragma unroll
    for (int k = 0; k < PJ; ++k) {
        const float* p = xyz + ((size_t)b * N + pbase + k * 256) * 3;
        px[k] = p[0]; py[k] = p[1]; pz[k] = p[2];
        tmin[k] = 1e30f; imin[k] = 0;
    }

    #pragma unroll 2
    for (int c = 0; c < CSL; ++c) {
        float4 q = c4[c];
        #pragma unroll
        for (int k = 0; k < PJ; ++k) {
            float t = q.w - px[k] * q.x - py[k] * q.y - pz[k] * q.z;
            bool lt = t < tmin[k];
            tmin[k] = lt ? t : tmin[k];
            imin[k] = lt ? c : imin[k];
        }
    }

    #pragma unroll
    for (int k = 0; k < PJ; ++k) {
        unsigned bits = __float_as_uint(tmin[k]);
        unsigned ord  = (bits & 0x80000000u) ? ~bits : (bits | 0x80000000u);
        unsigned long long key =
            ((unsigned long long)ord << 32) | (unsigned)(qb * CSL + imin[k]);
        atomicMin(best + (size_t)b * N + pbase + k * 256, key);
    }
}

// ---- kernel 3: MFMA (row-chunk x col-tile grid) -> u32 atomicMin ---------
__global__ __launch_bounds__(BLKT) void k_sp2p(const float* __restrict__ sp,
                                               const unsigned short* __restrict__ Afrag,
                                               unsigned* __restrict__ minsq) {
    __shared__ unsigned short lds[CHUNK * 16];   // 64 KB
    const int b = blockIdx.z, chunk = blockIdx.y;
    const int tid = threadIdx.x, wid = tid >> 6, lane = tid & 63;

    // stage 64 KB: 8 iters x (512 lanes x 16 B)
    const char* src = (const char*)(Afrag +
                        ((size_t)b * N + (size_t)chunk * CHUNK) * 16);
    #pragma unroll
    for (int it = 0; it < 8; ++it) {
        int off = it * 8192 + wid * 1024;
        __builtin_amdgcn_global_load_lds((gvoid_t*)(src + off + lane * 16),
                                         (svoid_t*)((char*)lds + off), 16, 0, 0);
    }

    // FR B-fragments per wave (overlaps staging latency)
    const int colbase = blockIdx.x * COLS_BLK + wid * (FR * 32) + (lane & 31);
    float pp[FR]; short8v bf[FR];
    #pragma unroll
    for (int f = 0; f < FR; ++f) {
        const float* p = sp + ((size_t)b * NSP + colbase + f * 32) * 3;
        float qx = p[0], qy = p[1], qz = p[2];
        pp[f] = qx * qx + qy * qy + qz * qz;
        unsigned short xh = f2b(qx), yh = f2b(qy), zh = f2b(qz);
        unsigned short xl = f2b(qx - b2f(xh));
        unsigned short yl = f2b(qy - b2f(yh));
        unsigned short zl = f2b(qz - b2f(zh));
        short8v v;
        if (lane < 32) {
            v[0] = (short)xh; v[1] = (short)yh; v[2] = (short)zh;
            v[3] = (short)xh; v[4] = (short)yh; v[5] = (short)zh;
            v[6] = (short)xl; v[7] = (short)yl;
        } else {
            v[0] = (short)zl; v[1] = (short)0x3F80; v[2] = (short)0x3F80;
            v[3] = 0; v[4] = 0; v[5] = 0; v[6] = 0; v[7] = 0;
        }
        bf[f] = v;
    }

    float run[FR];
    #pragma unroll
    for (int f = 0; f < FR; ++f) run[f] = 1e30f;

    __syncthreads();   // staging complete

    const unsigned short* ap = lds + lane * 8;
    #pragma unroll 1
    for (int t = 0; t < CHUNK / 32; ++t) {
        short8v a = *(const short8v*)(ap + (size_t)t * 512);
        #pragma unroll
        for (int f = 0; f < FR; ++f) {
            f32x16 d = mfma_v(a, bf[f]);
            float r0 = min3f(d[0],  d[1],  d[2]);
            float r1 = min3f(d[3],  d[4],  d[5]);
            float r2 = min3f(d[6],  d[7],  d[8]);
            float r3 = min3f(d[9],  d[10], d[11]);
            float r4 = min3f(d[12], d[13], d[14]);
            float r5 = min3f(r0, r1, d[15]);
            float r6 = min3f(r2, r3, r4);
            run[f] = min3f(run[f], r5, r6);
        }
    }

    // lanes l, l^32 hold the same col: combine, then one atomic per col
    #pragma unroll
    for (int f = 0; f < FR; ++f)
        run[f] = fminf(run[f], __shfl_xor(run[f], 32, 64));
    if (lane < 32) {
        unsigned* mb = minsq + (size_t)b * NSP + colbase;
        #pragma unroll
        for (int f = 0; f < FR; ++f) {
            float sq = fmaxf(2.0f * run[f] + pp[f], 0.0f);
            atomicMin(mb + f * 32, __float_as_uint(sq));
        }
    }
}

// ---- kernel 4: p2c finalize + group-max + ticketed final scalar ----------
__global__ __launch_bounds__(256) void k_fin(const unsigned long long* __restrict__ best,
                                             const unsigned* __restrict__ minsq,
                                             const float* __restrict__ xyz,
                                             const float* __restrict__ radius,
                                             float* __restrict__ acc,
                                             unsigned* __restrict__ counter,
                                             float* __restrict__ out) {
    const int tid = threadIdx.x;
    const int i = blockIdx.x * 256 + tid;   // [0, B*N) == [0, B*NSP)
    const int b = i >> 15;

    // p2c term
    unsigned long long k = best[i];
    int idx = (int)(k & 0xFFFFFFFFu);
    unsigned ord  = (unsigned)(k >> 32);
    unsigned bits = (ord & 0x80000000u) ? (ord ^ 0x80000000u) : ~ord;
    float tmin = __uint_as_float(bits);
    const float* p = xyz + (size_t)i * 3;
    float pp = p[0] * p[0] + p[1] * p[1] + p[2] * p[2];
    float cdp = sqrtf(fmaxf(2.0f * tmin + pp, 1e-12f));
    float val = fmaxf(cdp - radius[(size_t)b * NC + idx], 0.0f);

    // c2p term: group of S=32 consecutive minsq entries = one 32-lane half
    float cd = sqrtf(fmaxf(__uint_as_float(minsq[i]), 1e-12f));
    #pragma unroll
    for (int o = 16; o > 0; o >>= 1) cd = fmaxf(cd, __shfl_xor(cd, o, 64));

    float contrib = val * (1.0f / N) +
                    (((tid & 31) == 0) ? cd * (1.0f / NC) : 0.0f);
    #pragma unroll
    for (int o = 32; o > 0; o >>= 1) contrib += __shfl_down(contrib, o);
    __shared__ float wsum[4];
    if ((tid & 63) == 0) wsum[tid >> 6] = contrib;
    __syncthreads();
    if (tid == 0) atomicAdd(&acc[0], wsum[0] + wsum[1] + wsum[2] + wsum[3]);

    __shared__ int lastf;
    if (tid == 0) {
        __threadfence();
        unsigned old = atomicAdd(counter, 1u);
        lastf = (old == (unsigned)(gridDim.x - 1));
    }
    __syncthreads();
    if (lastf && tid == 0)
        out[0] = atomicAdd(&acc[0], 0.0f) * (1.0f / B);
}

extern "C" void kernel_launch(void* const* d_in, const int* in_sizes, int n_in,
                              void* d_out, int out_size, void* d_ws, size_t ws_size,
                              hipStream_t stream) {
    const float* centers = (const float*)d_in[0];
    const float* radius  = (const float*)d_in[1];
    const float* xyz     = (const float*)d_in[2];
    const float* sp      = (const float*)d_in[3];
    float* out = (float*)d_out;

    unsigned short*     Afrag = (unsigned short*)d_ws;                        // 2 MB
    unsigned long long* best  = (unsigned long long*)((char*)d_ws + (size_t)B * N * 32);
    unsigned* minsq  = (unsigned*)((char*)best + (size_t)B * N * 8);          // 256 KB
    float*    acc    = (float*)((char*)minsq + (size_t)B * NSP * 4);
    unsigned* counter = (unsigned*)acc + 1;

    hipLaunchKernelGGL(k_prep, dim3(B * N / 256), dim3(256), 0, stream,
                       xyz, Afrag, best, minsq, (unsigned*)acc);
    hipLaunchKernelGGL(k_p2c, dim3(N / (256 * PJ), NC / CSL, B), dim3(256), 0, stream,
                       centers, xyz, best);
    hipLaunchKernelGGL(k_sp2p, dim3(GRIDX, NCH, B), dim3(BLKT), 0, stream,
                       sp, Afrag, minsq);
    hipLaunchKernelGGL(k_fin, dim3(B * N / 256), dim3(256), 0, stream,
                       best, minsq, xyz, radius, acc, counter, out);
}

// Round 8
// 137.548 us; speedup vs baseline: 1.1520x; 1.0414x over previous
//
#include <hip/hip_runtime.h>

#define B   2
#define N   32768
#define NC  1024
#define S   32
#define NSP (NC * S)   // 32768

#define CHUNK 1024              // xyz rows staged per block (32 KB -> 4 blocks/CU)
#define NCH   (N / CHUNK)       // 32
#define BLKT  512               // 8 waves
#define FR    4                 // B-fragments (col tiles) per wave
#define COLS_BLK (8 * FR * 32)  // 1024
#define GRIDX (NSP / COLS_BLK)  // 32

#define PJ  2                   // points per thread in k_p2c
#define CSL 128                 // centers per slice in k_p2c

typedef __attribute__((ext_vector_type(8)))  short short8v;
typedef __attribute__((ext_vector_type(16))) float f32x16;
typedef const __attribute__((address_space(1))) void gvoid_t;
typedef __attribute__((address_space(3))) void svoid_t;

static __device__ __forceinline__ unsigned short f2b(float x) {
    unsigned u = __float_as_uint(x);
    return (unsigned short)((u + 0x7FFFu + ((u >> 16) & 1u)) >> 16);   // RNE
}
static __device__ __forceinline__ float b2f(unsigned short u) {
    return __uint_as_float(((unsigned)u) << 16);
}
static __device__ __forceinline__ float min3f(float a, float b, float c) {
    return fminf(fminf(a, b), c);   // clang fuses to v_min3_f32
}

// ws layout: Afrag 2MB | best u64 512KB | minsq u32 256KB | acc+counter 32B

// ---- kernel 1: build A-fragments + init best/minsq/acc -------------------
__global__ __launch_bounds__(256) void k_prep(const float* __restrict__ xyz,
                                              unsigned short* __restrict__ Afrag,
                                              unsigned long long* __restrict__ best,
                                              unsigned* __restrict__ minsq,
                                              unsigned* __restrict__ accw) {
    int i = blockIdx.x * 256 + threadIdx.x;   // [0, B*N) == [0, B*NSP)
    if (i < 2) accw[i] = 0u;                  // acc float + counter
    best[i]  = ~0ull;
    minsq[i] = 0x7F800000u;                   // +inf bits

    const float* q = xyz + (size_t)i * 3;
    float qx = q[0], qy = q[1], qz = q[2];
    float h = 0.5f * (qx * qx + qy * qy + qz * qz);
    unsigned short xh = f2b(-qx), yh = f2b(-qy), zh = f2b(-qz);
    unsigned short xl = f2b(-qx - b2f(xh));
    unsigned short yl = f2b(-qy - b2f(yh));
    unsigned short zl = f2b(-qz - b2f(zh));
    unsigned short hh = f2b(h), hl = f2b(h - b2f(hh));

    int b = i >> 15, j = i & (N - 1);
    int tile = j >> 5, r = j & 31;
    unsigned short* base = Afrag + ((size_t)b * N + (size_t)tile * 32) * 16;
    uint4 s0, s1;
    s0.x = (unsigned)xh | ((unsigned)yh << 16);
    s0.y = (unsigned)zh | ((unsigned)xl << 16);
    s0.z = (unsigned)yl | ((unsigned)zl << 16);
    s0.w = (unsigned)xh | ((unsigned)yh << 16);
    s1.x = (unsigned)zh | ((unsigned)hh << 16);
    s1.y = (unsigned)hl;
    s1.z = 0u; s1.w = 0u;
    *(uint4*)(base + (size_t)r * 8)        = s0;   // k=0..7   lane r
    *(uint4*)(base + (size_t)(r + 32) * 8) = s1;   // k=8..15  lane r+32
}

// ---- kernel 2: argmin over a 128-center slice, 2 points/thread -----------
__global__ __launch_bounds__(256) void k_p2c(const float* __restrict__ centers,
                                             const float* __restrict__ xyz,
                                             unsigned long long* __restrict__ best) {
    __shared__ float4 c4[CSL];
    const int b = blockIdx.z, qb = blockIdx.y, tid = threadIdx.x;

    const float* cb = centers + ((size_t)b * NC + qb * CSL) * 3;
    for (int g = tid; g < CSL / 4; g += 256) {
        float4 f0 = ((const float4*)cb)[g * 3 + 0];
        float4 f1 = ((const float4*)cb)[g * 3 + 1];
        float4 f2 = ((const float4*)cb)[g * 3 + 2];
        float x0 = f0.x, y0 = f0.y, z0 = f0.z;
        float x1 = f0.w, y1 = f1.x, z1 = f1.y;
        float x2 = f1.z, y2 = f1.w, z2 = f2.x;
        float x3 = f2.y, y3 = f2.z, z3 = f2.w;
        c4[g * 4 + 0] = make_float4(x0, y0, z0, 0.5f * (x0 * x0 + y0 * y0 + z0 * z0));
        c4[g * 4 + 1] = make_float4(x1, y1, z1, 0.5f * (x1 * x1 + y1 * y1 + z1 * z1));
        c4[g * 4 + 2] = make_float4(x2, y2, z2, 0.5f * (x2 * x2 + y2 * y2 + z2 * z2));
        c4[g * 4 + 3] = make_float4(x3, y3, z3, 0.5f * (x3 * x3 + y3 * y3 + z3 * z3));
    }
    __syncthreads();

    // 2 points per thread, stride-256 within a 512-point panel
    const int pbase = blockIdx.x * (256 * PJ) + tid;
    float px[PJ], py[PJ], pz[PJ], tmin[PJ];
    int imin[PJ];
    #pragma unroll
    for (int k = 0; k < PJ; ++k) {
        const float* p = xyz + ((size_t)b * N + pbase + k * 256) * 3;
        px[k] = p[0]; py[k] = p[1]; pz[k] = p[2];
        tmin[k] = 1e30f; imin[k] = 0;
    }

    #pragma unroll 4
    for (int c = 0; c < CSL; ++c) {
        float4 q = c4[c];
        #pragma unroll
        for (int k = 0; k < PJ; ++k) {
            float t = q.w - px[k] * q.x - py[k] * q.y - pz[k] * q.z;
            bool lt = t < tmin[k];
            tmin[k] = lt ? t : tmin[k];
            imin[k] = lt ? c : imin[k];
        }
    }

    #pragma unroll
    for (int k = 0; k < PJ; ++k) {
        unsigned bits = __float_as_uint(tmin[k]);
        unsigned ord  = (bits & 0x80000000u) ? ~bits : (bits | 0x80000000u);
        unsigned long long key =
            ((unsigned long long)ord << 32) | (unsigned)(qb * CSL + imin[k]);
        atomicMin(best + (size_t)b * N + pbase + k * 256, key);
    }
}

// ---- kernel 3: MFMA (row-chunk x col-tile grid) -> u32 atomicMin ---------
__global__ __launch_bounds__(BLKT) void k_sp2p(const float* __restrict__ sp,
                                               const unsigned short* __restrict__ Afrag,
                                               unsigned* __restrict__ minsq) {
    __shared__ unsigned short lds[CHUNK * 16];   // 32 KB
    const int b = blockIdx.z, chunk = blockIdx.y;
    const int tid = threadIdx.x, wid = tid >> 6, lane = tid & 63;

    // stage 32 KB: 4 iters x (512 lanes x 16 B)
    const char* src = (const char*)(Afrag +
                        ((size_t)b * N + (size_t)chunk * CHUNK) * 16);
    #pragma unroll
    for (int it = 0; it < 4; ++it) {
        int off = it * 8192 + wid * 1024;
        __builtin_amdgcn_global_load_lds((gvoid_t*)(src + off + lane * 16),
                                         (svoid_t*)((char*)lds + off), 16, 0, 0);
    }

    // FR B-fragments per wave (overlaps staging latency)
    const int colbase = blockIdx.x * COLS_BLK + wid * (FR * 32) + (lane & 31);
    float pp[FR]; short8v bf[FR];
    #pragma unroll
    for (int f = 0; f < FR; ++f) {
        const float* p = sp + ((size_t)b * NSP + colbase + f * 32) * 3;
        float qx = p[0], qy = p[1], qz = p[2];
        pp[f] = qx * qx + qy * qy + qz * qz;
        unsigned short xh = f2b(qx), yh = f2b(qy), zh = f2b(qz);
        unsigned short xl = f2b(qx - b2f(xh));
        unsigned short yl = f2b(qy - b2f(yh));
        unsigned short zl = f2b(qz - b2f(zh));
        short8v v;
        if (lane < 32) {
            v[0] = (short)xh; v[1] = (short)yh; v[2] = (short)zh;
            v[3] = (short)xh; v[4] = (short)yh; v[5] = (short)zh;
            v[6] = (short)xl; v[7] = (short)yl;
        } else {
            v[0] = (short)zl; v[1] = (short)0x3F80; v[2] = (short)0x3F80;
            v[3] = 0; v[4] = 0; v[5] = 0; v[6] = 0; v[7] = 0;
        }
        bf[f] = v;
    }
    f32x16 zero;
    #pragma unroll
    for (int i = 0; i < 16; ++i) zero[i] = 0.0f;

    float run[FR];
    #pragma unroll
    for (int f = 0; f < FR; ++f) run[f] = 1e30f;

    __syncthreads();   // staging complete

    const unsigned short* ap = lds + lane * 8;
    #pragma unroll 2
    for (int t = 0; t < CHUNK / 32; ++t) {
        short8v a = *(const short8v*)(ap + (size_t)t * 512);
        #pragma unroll
        for (int f = 0; f < FR; ++f) {
            f32x16 d = __builtin_amdgcn_mfma_f32_32x32x16_bf16(a, bf[f], zero, 0, 0, 0);
            float r0 = min3f(d[0],  d[1],  d[2]);
            float r1 = min3f(d[3],  d[4],  d[5]);
            float r2 = min3f(d[6],  d[7],  d[8]);
            float r3 = min3f(d[9],  d[10], d[11]);
            float r4 = min3f(d[12], d[13], d[14]);
            float r5 = min3f(r0, r1, d[15]);
            float r6 = min3f(r2, r3, r4);
            run[f] = min3f(run[f], r5, r6);
        }
    }

    // lanes l, l^32 hold the same col: combine, then one atomic per col
    #pragma unroll
    for (int f = 0; f < FR; ++f)
        run[f] = fminf(run[f], __shfl_xor(run[f], 32, 64));
    if (lane < 32) {
        unsigned* mb = minsq + (size_t)b * NSP + colbase;
        #pragma unroll
        for (int f = 0; f < FR; ++f) {
            float sq = fmaxf(2.0f * run[f] + pp[f], 0.0f);
            atomicMin(mb + f * 32, __float_as_uint(sq));
        }
    }
}

// ---- kernel 4: p2c finalize + group-max + ticketed final scalar ----------
__global__ __launch_bounds__(256) void k_fin(const unsigned long long* __restrict__ best,
                                             const unsigned* __restrict__ minsq,
                                             const float* __restrict__ xyz,
                                             const float* __restrict__ radius,
                                             float* __restrict__ acc,
                                             unsigned* __restrict__ counter,
                                             float* __restrict__ out) {
    const int tid = threadIdx.x;
    const int i = blockIdx.x * 256 + tid;   // [0, B*N) == [0, B*NSP)
    const int b = i >> 15;

    // p2c term
    unsigned long long k = best[i];
    int idx = (int)(k & 0xFFFFFFFFu);
    unsigned ord  = (unsigned)(k >> 32);
    unsigned bits = (ord & 0x80000000u) ? (ord ^ 0x80000000u) : ~ord;
    float tmin = __uint_as_float(bits);
    const float* p = xyz + (size_t)i * 3;
    float pp = p[0] * p[0] + p[1] * p[1] + p[2] * p[2];
    float cdp = sqrtf(fmaxf(2.0f * tmin + pp, 1e-12f));
    float val = fmaxf(cdp - radius[(size_t)b * NC + idx], 0.0f);

    // c2p term: group of S=32 consecutive minsq entries = one 32-lane half
    float cd = sqrtf(fmaxf(__uint_as_float(minsq[i]), 1e-12f));
    #pragma unroll
    for (int o = 16; o > 0; o >>= 1) cd = fmaxf(cd, __shfl_xor(cd, o, 64));

    float contrib = val * (1.0f / N) +
                    (((tid & 31) == 0) ? cd * (1.0f / NC) : 0.0f);
    #pragma unroll
    for (int o = 32; o > 0; o >>= 1) contrib += __shfl_down(contrib, o);
    __shared__ float wsum[4];
    if ((tid & 63) == 0) wsum[tid >> 6] = contrib;
    __syncthreads();
    if (tid == 0) atomicAdd(&acc[0], wsum[0] + wsum[1] + wsum[2] + wsum[3]);

    __shared__ int lastf;
    if (tid == 0) {
        __threadfence();
        unsigned old = atomicAdd(counter, 1u);
        lastf = (old == (unsigned)(gridDim.x - 1));
    }
    __syncthreads();
    if (lastf && tid == 0)
        out[0] = atomicAdd(&acc[0], 0.0f) * (1.0f / B);
}

extern "C" void kernel_launch(void* const* d_in, const int* in_sizes, int n_in,
                              void* d_out, int out_size, void* d_ws, size_t ws_size,
                              hipStream_t stream) {
    const float* centers = (const float*)d_in[0];
    const float* radius  = (const float*)d_in[1];
    const float* xyz     = (const float*)d_in[2];
    const float* sp      = (const float*)d_in[3];
    float* out = (float*)d_out;

    unsigned short*     Afrag = (unsigned short*)d_ws;                        // 2 MB
    unsigned long long* best  = (unsigned long long*)((char*)d_ws + (size_t)B * N * 32);
    unsigned* minsq  = (unsigned*)((char*)best + (size_t)B * N * 8);          // 256 KB
    float*    acc    = (float*)((char*)minsq + (size_t)B * NSP * 4);
    unsigned* counter = (unsigned*)acc + 1;

    hipLaunchKernelGGL(k_prep, dim3(B * N / 256), dim3(256), 0, stream,
                       xyz, Afrag, best, minsq, (unsigned*)acc);
    hipLaunchKernelGGL(k_p2c, dim3(N / (256 * PJ), NC / CSL, B), dim3(256), 0, stream,
                       centers, xyz, best);
    hipLaunchKernelGGL(k_sp2p, dim3(GRIDX, NCH, B), dim3(BLKT), 0, stream,
                       sp, Afrag, minsq);
    hipLaunchKernelGGL(k_fin, dim3(B * N / 256), dim3(256), 0, stream,
                       best, minsq, xyz, radius, acc, counter, out);
}